// Round 9
// baseline (242.391 us; speedup 1.0000x reference)
//
#include <hip/hip_runtime.h>
#include <hip/hip_bf16.h>

// Problem constants
#define B_    8
#define C_    96
#define N_    3136      // 56*56
#define COUT_ 192
#define NTOK_ 25088     // B_*N_
#define BN_EPS 1e-5f

#define CROW 200        // conv cat LDS token-row stride in bf16 (192+8): 400B odd*16 -> conflict-free
#define BNC  (B_ * N_ * C_)
#define NSPLIT 4
#define NT98  98        // 32-row K tiles per batch (3136/32)

typedef __hip_bfloat16 bf16;
typedef unsigned short u16;
typedef unsigned int u32;
typedef __attribute__((ext_vector_type(8))) short short8;    // 8 bf16 = 16B (MFMA A/B frag)
typedef __attribute__((ext_vector_type(16))) float f32x16;   // 32x32 MFMA C/D frag

__device__ __forceinline__ u16 f2bf(float f) {
    union { __hip_bfloat16 h; u16 u; } cv;
    cv.h = __float2bfloat16(f);
    return cv.u;
}
__device__ __forceinline__ float bf2f(u16 v) {
    union { u16 u; __hip_bfloat16 h; } cv;
    cv.u = v;
    return __bfloat162float(cv.h);
}
__device__ __forceinline__ u32 packbf2(float lo, float hi) {
    return ((u32)f2bf(hi) << 16) | (u32)f2bf(lo);
}

// async global->LDS DMA, 16B per lane: LDS dest = WAVE-UNIFORM base + lane*16.
__device__ __forceinline__ void gload_lds16(const void* g, void* l) {
    __builtin_amdgcn_global_load_lds((const __attribute__((address_space(1))) void*)g,
                                     (__attribute__((address_space(3))) void*)l,
                                     16, 0, 0);
}

// fragment offset in xf arrays: frag (b-pre-offset pointer, tile t, chunk kc)
// = ((t*6)+kc) * 512 u16 (1KB). Lane l holds token t*32+(l&31),
// channels kc*16+(l>>5)*8 .. +8 — exactly the mfma_32x32x16 A/B layout.
__device__ __forceinline__ size_t foff(int t, int kc) {
    return ((size_t)t * 6 + kc) << 9;
}

// ---------------------------------------------------------------------------
// K1: x [B][C][N] fp32 ->
//   xf_hi/xf_lo [B][98][6][512] bf16 fragment-major (K and Q frags, hi/lo)
//   xc_hi [B][C][N] bf16 (channel-major, V staged from here)
//   norm2 per-token squared norms.
// R20: replaces token-major xt_hi/xt_lo with fragment-major xf so K2 can
// load K/Q frags as single coalesced dwordx4 from global (L1/L2-hot).
__global__ __launch_bounds__(256) void transpose_split(const float* __restrict__ x,
                                                       u16* __restrict__ xf_hi,
                                                       u16* __restrict__ xf_lo,
                                                       u16* __restrict__ xc_hi,
                                                       float* __restrict__ norm2) {
    __shared__ float tile[32][33];
    __shared__ float nrm[32];
    const int nb = blockIdx.x * 32;     // token base (tile t = nb/32)
    const int cb = blockIdx.y * 32;     // channel base (kc = cb/16 + {0,1})
    const int b  = blockIdx.z;
    const int tid = threadIdx.x;
    const int tx = tid & 31;
    const int ty = tid >> 5;
    if (tid < 32) nrm[tid] = 0.0f;
    float psum = 0.0f;
#pragma unroll
    for (int r = 0; r < 32; r += 8) {
        size_t idx = ((size_t)b * C_ + cb + ty + r) * N_ + nb + tx;
        float v = x[idx];
        tile[ty + r][tx] = v;
        xc_hi[idx] = f2bf(v);
        psum = fmaf(v, v, psum);
    }
    __syncthreads();               // tile visible; nrm init done
    atomicAdd(&nrm[tx], psum);     // LDS atomic, 8 adders per slot

    // phase 2: fragment-major hi/lo writes. 128 items (kc_i in 0..1, lane l
    // in 0..63); threads 0-127 write hi, 128-255 write lo. 16B/thread,
    // contiguous 1KB per frag.
    {
        const int item  = tid & 127;
        const int is_lo = tid >> 7;
        const int kc_i  = item >> 6;
        const int l     = item & 63;
        const int kcg   = (cb >> 4) + kc_i;
        union { u16 a[8]; short8 v8; } o;
#pragma unroll
        for (int j = 0; j < 8; j++) {
            float v = tile[kc_i * 16 + ((l >> 5) * 8) + j][l & 31];
            u16 h = f2bf(v);
            o.a[j] = is_lo ? f2bf(v - bf2f(h)) : h;
        }
        u16* dst = (is_lo ? xf_lo : xf_hi) +
                   ((size_t)b * NT98 * 6 << 9) + foff(nb >> 5, kcg) + l * 8;
        *(short8*)dst = o.v8;
    }
    __syncthreads();               // nrm complete
    if (tid < 32)
        atomicAdd(&norm2[(size_t)b * N_ + nb + tid], nrm[tid]);
}

// K1b: conv_w [O][2C] fp32 -> whi/wlo bf16 (same [o][c] layout, hi/lo split)
__global__ __launch_bounds__(256) void cast_w(const float* __restrict__ w,
                                              u16* __restrict__ whi,
                                              u16* __restrict__ wlo) {
    int i = blockIdx.x * 256 + threadIdx.x;
    if (i >= COUT_ * 2 * C_) return;
    float v = w[i];
    u16 h = f2bf(v);
    whi[i] = h;
    wlo[i] = f2bf(v - bf2f(h));
}

// K1c: global max of norm2 — multi-block; norm2>=0 -> int-bits atomicMax.
__global__ __launch_bounds__(256) void norm_max(const float* __restrict__ norm2,
                                                int* __restrict__ maxbits) {
    const int tid = blockIdx.x * 256 + threadIdx.x;
    float m = 0.0f;
    for (int i = tid; i < NTOK_; i += gridDim.x * 256) m = fmaxf(m, norm2[i]);
#pragma unroll
    for (int d = 1; d < 64; d <<= 1) m = fmaxf(m, __shfl_xor(m, d));
    if ((threadIdx.x & 63) == 0) atomicMax(maxbits, __float_as_int(m));
}

// ---------------------------------------------------------------------------
// K2: MFMA flash attention, transposed-S, 4-way split-K.
// R20: K2 is LDS-BW-bound (92 B/cy/CU vs ~85-128 ceiling; confirmed R16+R19,
// and K LDS reads are 4x wave-redundant). Fix: K/Q frags load DIRECT from
// the fragment-major xf arrays — single coalesced dwordx4 per frag (this is
// what R18's scattered V-direct was missing). Only V stays in LDS (verified
// DMA path). LDS/block-tile: reads 73.7->24.6KB, writes 22->7.4KB. Math is
// bit-identical to R19 (same MFMA sequence) -> absmax must stay 0.03125.
// K loaded in 2 batches of 3 chunks (24 K-regs peak) for the 3-wave budget.
__global__ __launch_bounds__(256, 3) void flash_attn_mfma32(const u16* __restrict__ xf_hi,
                                                            const u16* __restrict__ xf_lo,
                                                            const u16* __restrict__ xc_hi,
                                                            const float* __restrict__ norm2,
                                                            const int* __restrict__ maxbits,
                                                            float* __restrict__ attT,
                                                            float* __restrict__ l_arr) {
    __shared__ __align__(16) char VL[2][8192];   // V: 96 ch x 80B rows (+pad)
    const int b     = blockIdx.y;
    const int i0    = blockIdx.x * 128;
    const int split = blockIdx.z;
    const int kt0   = (NT98 * split) / NSPLIT;
    const int kt1   = (NT98 * (split + 1)) / NSPLIT;
    const int tid   = threadIdx.x;
    const int lane  = tid & 63;
    const int w     = tid >> 6;
    const int col   = lane & 31;
    const int g     = lane >> 5;

    const u16* fh = xf_hi + ((size_t)b * NT98 * 6 << 9);
    const u16* fl = xf_lo + ((size_t)b * NT98 * 6 << 9);
    const u16* vh = xc_hi + (size_t)b * C_ * N_;

    // V staging: 8 DMA slots of 1KB per buffer; wave w owns slots w, w+4.
    u32 vloff[2], vdofs[2];
#pragma unroll
    for (int j = 0; j < 2; j++) {
        int s = w + 4 * j;
        int p = s * 64 + lane;        // 16B chunk 0..511 (480 data + pad)
        int ch = p / 5, c = p % 5;
        if (c > 3) c = 3;
        vloff[j] = (ch < 96) ? (u32)(ch * (N_ * 2) + c * 16) : 0u;
        vdofs[j] = (u32)(s * 1024);
    }

    // Q frags: one coalesced dwordx4 per chunk (wave's q-tile = bx*4+w)
    int qt = blockIdx.x * 4 + w;
    if (qt > NT98 - 1) qt = NT98 - 1;
    const int qrow  = i0 + w * 32 + col;
    const int qrowc = qrow < N_ ? qrow : N_ - 1;
    short8 qh[6], ql[6];
#pragma unroll
    for (int kc = 0; kc < 6; kc++) {
        qh[kc] = *(const short8*)&fh[foff(qt, kc) + lane * 8];
        ql[kc] = *(const short8*)&fl[foff(qt, kc) + lane * 8];
    }
    const float maxn2 = __int_as_float(*maxbits);
    const float m_i   = sqrtf(norm2[(size_t)b * N_ + qrowc] * maxn2);
    float l_acc = 0.0f;
    f32x16 O0 = {0}, O1 = {0}, O2 = {0};

    // stage V tile kt into buffer nbuf (2 async DMA per wave)
    auto stageV = [&](int nbuf, int kt) {
        const u32 ktV = (u32)kt * 64u;     // 32 tokens * 2B
#pragma unroll
        for (int j = 0; j < 2; j++)
            gload_lds16((const char*)vh + ktV + vloff[j], &VL[nbuf][0] + vdofs[j]);
    };

    stageV(0, kt0);
    __syncthreads();

    const int g16 = g * 16;
    int buf = 0;
    for (int kt = kt0; kt < kt1; kt++) {
        // (1) prefetch next V tile into back buffer
        if (kt + 1 < kt1) stageV(buf ^ 1, kt + 1);

        // (2) QK^T: K frags direct from global (L1-hot, coalesced), 2 batches
        f32x16 S = {0};
#pragma unroll
        for (int hf = 0; hf < 2; hf++) {
            short8 kh[3], kl[3];
#pragma unroll
            for (int j = 0; j < 3; j++) {
                kh[j] = *(const short8*)&fh[foff(kt, hf * 3 + j) + lane * 8];
                kl[j] = *(const short8*)&fl[foff(kt, hf * 3 + j) + lane * 8];
            }
            __builtin_amdgcn_s_setprio(1);
#pragma unroll
            for (int j = 0; j < 3; j++) {
                const int kc = hf * 3 + j;
                S = __builtin_amdgcn_mfma_f32_32x32x16_bf16(kh[j], ql[kc], S, 0, 0, 0);
                S = __builtin_amdgcn_mfma_f32_32x32x16_bf16(kl[j], qh[kc], S, 0, 0, 0);
                S = __builtin_amdgcn_mfma_f32_32x32x16_bf16(kh[j], qh[kc], S, 0, 0, 0);
            }
            __builtin_amdgcn_s_setprio(0);
        }

        // (3) softmax numerators + bf16 pack
        float p[16];
#pragma unroll
        for (int r = 0; r < 16; r++) {
            p[r] = __expf(S[r] - m_i);
            l_acc += p[r];
        }
        u32 w8[8];
#pragma unroll
        for (int q = 0; q < 8; q++) w8[q] = packbf2(p[2 * q], p[2 * q + 1]);

        // (4) PV from V-LDS (80B rows: conflict-free)
        __builtin_amdgcn_s_setprio(1);
#pragma unroll
        for (int kc = 0; kc < 2; kc++) {
            const int qb = kc * 4;
            u32 a0 = w8[qb + 0], a1 = w8[qb + 1];
            u32 a2 = w8[qb + 2], a3 = w8[qb + 3];
            u32 s0 = __shfl_xor((int)a0, 32), s1 = __shfl_xor((int)a1, 32);
            u32 s2 = __shfl_xor((int)a2, 32), s3 = __shfl_xor((int)a3, 32);
            union { short8 v; u32 u[4]; } Bf;
            Bf.u[0] = g ? s2 : a0;
            Bf.u[1] = g ? s3 : a1;
            Bf.u[2] = g ? a2 : s0;
            Bf.u[3] = g ? a3 : s1;
            const int vo = col * 80 + kc * 32 + g16;
            short8 v0 = *(const short8*)(&VL[buf][0] + vo);
            short8 v1 = *(const short8*)(&VL[buf][0] + vo + 2560);   // +32 ch
            short8 v2 = *(const short8*)(&VL[buf][0] + vo + 5120);   // +64 ch
            O0 = __builtin_amdgcn_mfma_f32_32x32x16_bf16(v0, Bf.v, O0, 0, 0, 0);
            O1 = __builtin_amdgcn_mfma_f32_32x32x16_bf16(v1, Bf.v, O1, 0, 0, 0);
            O2 = __builtin_amdgcn_mfma_f32_32x32x16_bf16(v2, Bf.v, O2, 0, 0, 0);
        }
        __builtin_amdgcn_s_setprio(0);

        __syncthreads();     // drains my V-DMAs + all waves' V reads done
        buf ^= 1;
    }

    if (qrow < N_) {
        float* ab = attT + (size_t)b * C_ * N_ + qrow;
#pragma unroll
        for (int r = 0; r < 16; r++) {
            int c = (r & 3) + 8 * (r >> 2) + 4 * g;
            atomicAdd(&ab[(size_t)(c)      * N_], O0[r]);
            atomicAdd(&ab[(size_t)(c + 32) * N_], O1[r]);
            atomicAdd(&ab[(size_t)(c + 64) * N_], O2[r]);
        }
        float l_tot = l_acc + __shfl_xor(l_acc, 32);
        if (g == 0) atomicAdd(&l_arr[(size_t)b * N_ + qrow], l_tot);
    }
}

// ---------------------------------------------------------------------------
// K3: MFMA 1x1 conv (R17 32-token/128-thread version; unchanged)
__global__ __launch_bounds__(128, 3) void conv_mfma(const float* __restrict__ x,
                                                    const float* __restrict__ attT,
                                                    const float* __restrict__ l_arr,
                                                    const u16* __restrict__ whi,
                                                    const u16* __restrict__ wlo,
                                                    const float* __restrict__ convb,
                                                    float* __restrict__ y) {
    __shared__ u16 ch[32 * CROW];
    __shared__ u16 cl[32 * CROW];
    __shared__ float invl[32];
    const int b   = blockIdx.x / (N_ / 32);
    const int n0  = (blockIdx.x % (N_ / 32)) * 32;
    const int tid = threadIdx.x;

    if (tid < 32) invl[tid] = 1.0f / l_arr[(size_t)b * N_ + n0 + tid];
    __syncthreads();

    const float* xb = x    + (size_t)b * C_ * N_ + n0;
    const float* ab = attT + (size_t)b * C_ * N_ + n0;
    for (int e = tid; e < 32 * C_; e += 128) {
        int c = e >> 5, t = e & 31;
        float xv = xb[(size_t)c * N_ + t];
        float au = ab[(size_t)c * N_ + t];
        float xj = fmaxf(xv - au * invl[t], 0.0f);
        u16 h1 = f2bf(xv);
        ch[t * CROW + c] = h1;
        cl[t * CROW + c] = f2bf(xv - bf2f(h1));
        u16 h2 = f2bf(xj);
        ch[t * CROW + C_ + c] = h2;
        cl[t * CROW + C_ + c] = f2bf(xj - bf2f(h2));
    }
    __syncthreads();

    const int lane = tid & 63;
    const int w    = tid >> 6;        // 0..1
    const int col  = lane & 31;       // token within tile
    const int g    = lane >> 5;
    const int m0   = w * 3;           // wave's 3 m-tiles (96 channels)

    f32x16 A[3] = {{0}, {0}, {0}};
#pragma unroll
    for (int ks = 0; ks < 12; ks++) {
        const int k0 = ks * 16;
        short8 bh = *(const short8*)&ch[col * CROW + k0 + g * 8];
        short8 bl = *(const short8*)&cl[col * CROW + k0 + g * 8];
#pragma unroll
        for (int mt = 0; mt < 3; mt++) {
            const size_t wo = (size_t)((m0 + mt) * 32 + col) * (2 * C_) + k0 + g * 8;
            short8 ah = *(const short8*)&whi[wo];
            short8 al = *(const short8*)&wlo[wo];
            A[mt] = __builtin_amdgcn_mfma_f32_32x32x16_bf16(ah, bl, A[mt], 0, 0, 0);
            A[mt] = __builtin_amdgcn_mfma_f32_32x32x16_bf16(al, bh, A[mt], 0, 0, 0);
            A[mt] = __builtin_amdgcn_mfma_f32_32x32x16_bf16(ah, bh, A[mt], 0, 0, 0);
        }
    }

    float* yb = y + (size_t)b * COUT_ * N_ + n0 + col;
#pragma unroll
    for (int mt = 0; mt < 3; mt++)
#pragma unroll
        for (int r = 0; r < 16; r++) {
            int o = (m0 + mt) * 32 + (r & 3) + 8 * (r >> 2) + 4 * g;
            yb[(size_t)o * N_] = A[mt][r] + convb[o];
        }
}

// ---------------------------------------------------------------------------
// K4a: per-(b,channel) partial BN sums (distinct output lines, no contention)
__global__ __launch_bounds__(256) void bn_partial(const float* __restrict__ y,
                                                  float* __restrict__ pb) {
    const int o   = blockIdx.x;
    const int b   = blockIdx.y;
    const int tid = threadIdx.x;
    float s = 0.0f, q = 0.0f;
    const float4* p = (const float4*)(y + (size_t)(b * COUT_ + o) * N_);
    for (int i = tid; i < N_ / 4; i += 256) {
        float4 v = p[i];
        s += v.x + v.y + v.z + v.w;
        q += v.x * v.x + v.y * v.y + v.z * v.z + v.w * v.w;
    }
#pragma unroll
    for (int d = 1; d < 64; d <<= 1) {
        s += __shfl_xor(s, d);
        q += __shfl_xor(q, d);
    }
    __shared__ float wss[4], wqq[4];
    if ((tid & 63) == 0) { wss[tid >> 6] = s; wqq[tid >> 6] = q; }
    __syncthreads();
    if (tid == 0) {
        pb[b * COUT_ + o]                = wss[0] + wss[1] + wss[2] + wss[3];
        pb[B_ * COUT_ + b * COUT_ + o]   = wqq[0] + wqq[1] + wqq[2] + wqq[3];
    }
}

// K4b: reduce partials -> scale/shift
__global__ __launch_bounds__(192) void bn_finish(const float* __restrict__ pb,
                                                 const float* __restrict__ gamma,
                                                 const float* __restrict__ beta,
                                                 float* __restrict__ ss) {
    const int o = threadIdx.x;
    float s = 0.0f, q = 0.0f;
#pragma unroll
    for (int b = 0; b < B_; b++) {
        s += pb[b * COUT_ + o];
        q += pb[B_ * COUT_ + b * COUT_ + o];
    }
    const float invn = 1.0f / (float)NTOK_;
    float mean = s * invn;
    float var  = q * invn - mean * mean;
    float sc   = gamma[o] * rsqrtf(var + BN_EPS);
    ss[o]         = sc;
    ss[COUT_ + o] = beta[o] - mean * sc;
}

// K5: y -> BN affine -> exact GELU -> fp32 out
__global__ __launch_bounds__(256) void bn_gelu_out(const float* __restrict__ y,
                                                   const float* __restrict__ ss,
                                                   float* __restrict__ out) {
    const int total4 = (B_ * COUT_ * N_) / 4;
    int i = blockIdx.x * 256 + threadIdx.x;
    if (i >= total4) return;
    int base = i * 4;
    int o = (base / N_) % COUT_;
    float sc = ss[o], sh = ss[COUT_ + o];
    float4 v = *(const float4*)&y[base];
    float u0 = fmaf(v.x, sc, sh), u1 = fmaf(v.y, sc, sh);
    float u2 = fmaf(v.z, sc, sh), u3 = fmaf(v.w, sc, sh);
    const float k = 0.70710678118654752f;
    float4 g;
    g.x = 0.5f * u0 * (1.0f + erff(u0 * k));
    g.y = 0.5f * u1 * (1.0f + erff(u1 * k));
    g.z = 0.5f * u2 * (1.0f + erff(u2 * k));
    g.w = 0.5f * u3 * (1.0f + erff(u3 * k));
    *(float4*)&out[base] = g;
}

// ---------------------------------------------------------------------------
extern "C" void kernel_launch(void* const* d_in, const int* in_sizes, int n_in,
                              void* d_out, int out_size, void* d_ws, size_t ws_size,
                              hipStream_t stream) {
    const float* x     = (const float*)d_in[0];
    const float* w     = (const float*)d_in[1];
    const float* cb    = (const float*)d_in[2];
    const float* gamma = (const float*)d_in[3];
    const float* beta  = (const float*)d_in[4];

    u16* xf_hi = (u16*)d_ws;                         // BNC bf16 (fragment-major)
    u16* xf_lo = xf_hi + (size_t)BNC;                // BNC
    u16* xc_hi = xf_lo + (size_t)BNC;                // BNC (channel-major, V)
    float* attT  = (float*)(xc_hi + (size_t)BNC);    // BNC fp32
    u16* whi   = (u16*)(attT + (size_t)BNC);         // 192*192 bf16
    u16* wlo   = whi + COUT_ * 2 * C_;               // 192*192 bf16
    float* y     = (float*)(wlo + COUT_ * 2 * C_);   // B*COUT*N fp32
    float* ss    = y + (size_t)B_ * COUT_ * N_;      // 2*COUT
    float* l_arr = ss + 2 * COUT_;                   // NTOK
    float* norm2 = l_arr + NTOK_;                    // NTOK
    int*   maxb  = (int*)(norm2 + NTOK_);            // 1
    float* pb    = attT;                             // 2*B*COUT partials (attT dead after conv)

    hipMemsetAsync(l_arr, 0, NTOK_ * sizeof(float), stream);
    hipMemsetAsync(norm2, 0, NTOK_ * sizeof(float), stream);
    hipMemsetAsync(maxb, 0, sizeof(int), stream);
    hipMemsetAsync(attT, 0, (size_t)BNC * sizeof(float), stream);

    transpose_split<<<dim3(N_ / 32, C_ / 32, B_), 256, 0, stream>>>(x, xf_hi, xf_lo, xc_hi, norm2);
    cast_w<<<dim3((COUT_ * 2 * C_ + 255) / 256), 256, 0, stream>>>(w, whi, wlo);
    norm_max<<<dim3(25), 256, 0, stream>>>(norm2, maxb);
    flash_attn_mfma32<<<dim3((N_ + 127) / 128, B_, NSPLIT), 256, 0, stream>>>(
        xf_hi, xf_lo, xc_hi, norm2, maxb, attT, l_arr);
    conv_mfma<<<dim3(B_ * (N_ / 32)), 128, 0, stream>>>(x, attT, l_arr, whi, wlo, cb, y);
    bn_partial<<<dim3(COUT_, B_), 256, 0, stream>>>(y, pb);
    bn_finish<<<dim3(1), 192, 0, stream>>>(pb, gamma, beta, ss);
    bn_gelu_out<<<dim3((B_ * COUT_ * N_ / 4 + 255) / 256), 256, 0, stream>>>(y, ss, (float*)d_out);
}

// Round 10
// 232.856 us; speedup vs baseline: 1.0409x; 1.0409x over previous
//
#include <hip/hip_runtime.h>
#include <hip/hip_bf16.h>

// Problem constants
#define B_    8
#define C_    96
#define N_    3136      // 56*56
#define COUT_ 192
#define NTOK_ 25088     // B_*N_
#define BN_EPS 1e-5f

#define CROW 200        // conv cat LDS token-row stride in bf16 (192+8): 400B odd*16 -> conflict-free
#define BNC  (B_ * N_ * C_)
#define NSPLIT 4
#define NT98  98        // 32-row K tiles per batch (3136/32)

// K2 LDS per buffer: Kh frags 6KB (frag kc at kc*1024, lane*16 within) |
// V 8KB at +6144 (96 ch x 80B rows + pad). x2 buffers = 28672 B.
#define K2_V_OFF 6144
#define K2_BUFSZ 14336

typedef __hip_bfloat16 bf16;
typedef unsigned short u16;
typedef unsigned int u32;
typedef __attribute__((ext_vector_type(8))) short short8;    // 8 bf16 = 16B (MFMA A/B frag)
typedef __attribute__((ext_vector_type(16))) float f32x16;   // 32x32 MFMA C/D frag

__device__ __forceinline__ u16 f2bf(float f) {
    union { __hip_bfloat16 h; u16 u; } cv;
    cv.h = __float2bfloat16(f);
    return cv.u;
}
__device__ __forceinline__ float bf2f(u16 v) {
    union { u16 u; __hip_bfloat16 h; } cv;
    cv.u = v;
    return __bfloat162float(cv.h);
}
__device__ __forceinline__ u32 packbf2(float lo, float hi) {
    return ((u32)f2bf(hi) << 16) | (u32)f2bf(lo);
}

// async global->LDS DMA, 16B per lane: LDS dest = WAVE-UNIFORM base + lane*16.
__device__ __forceinline__ void gload_lds16(const void* g, void* l) {
    __builtin_amdgcn_global_load_lds((const __attribute__((address_space(1))) void*)g,
                                     (__attribute__((address_space(3))) void*)l,
                                     16, 0, 0);
}

// fragment offset in xf arrays: frag (b-pre-offset pointer, tile t, chunk kc)
// = ((t*6)+kc) * 512 u16 (1KB). Lane l holds token t*32+(l&31),
// channels kc*16+(l>>5)*8 .. +8 — exactly the mfma_32x32x16 A/B layout.
__device__ __forceinline__ size_t foff(int t, int kc) {
    return ((size_t)t * 6 + kc) << 9;
}

// ---------------------------------------------------------------------------
// K1: x [B][C][N] fp32 ->
//   xf_hi/xf_lo [B][98][6][512] bf16 fragment-major (K and Q frags, hi/lo)
//   xc_hi [B][C][N] bf16 (channel-major, V staged from here)
//   norm2 per-token squared norms.  (R20 version — HW-verified correct.)
__global__ __launch_bounds__(256) void transpose_split(const float* __restrict__ x,
                                                       u16* __restrict__ xf_hi,
                                                       u16* __restrict__ xf_lo,
                                                       u16* __restrict__ xc_hi,
                                                       float* __restrict__ norm2) {
    __shared__ float tile[32][33];
    __shared__ float nrm[32];
    const int nb = blockIdx.x * 32;     // token base (tile t = nb/32)
    const int cb = blockIdx.y * 32;     // channel base (kc = cb/16 + {0,1})
    const int b  = blockIdx.z;
    const int tid = threadIdx.x;
    const int tx = tid & 31;
    const int ty = tid >> 5;
    if (tid < 32) nrm[tid] = 0.0f;
    float psum = 0.0f;
#pragma unroll
    for (int r = 0; r < 32; r += 8) {
        size_t idx = ((size_t)b * C_ + cb + ty + r) * N_ + nb + tx;
        float v = x[idx];
        tile[ty + r][tx] = v;
        xc_hi[idx] = f2bf(v);
        psum = fmaf(v, v, psum);
    }
    __syncthreads();               // tile visible; nrm init done
    atomicAdd(&nrm[tx], psum);     // LDS atomic, 8 adders per slot

    // phase 2: fragment-major hi/lo writes. 128 items (kc_i in 0..1, lane l
    // in 0..63); threads 0-127 write hi, 128-255 write lo. 16B/thread.
    {
        const int item  = tid & 127;
        const int is_lo = tid >> 7;
        const int kc_i  = item >> 6;
        const int l     = item & 63;
        const int kcg   = (cb >> 4) + kc_i;
        union { u16 a[8]; short8 v8; } o;
#pragma unroll
        for (int j = 0; j < 8; j++) {
            float v = tile[kc_i * 16 + ((l >> 5) * 8) + j][l & 31];
            u16 h = f2bf(v);
            o.a[j] = is_lo ? f2bf(v - bf2f(h)) : h;
        }
        u16* dst = (is_lo ? xf_lo : xf_hi) +
                   ((size_t)b * NT98 * 6 << 9) + foff(nb >> 5, kcg) + l * 8;
        *(short8*)dst = o.v8;
    }
    __syncthreads();               // nrm complete
    if (tid < 32)
        atomicAdd(&norm2[(size_t)b * N_ + nb + tid], nrm[tid]);
}

// K1b: conv_w [O][2C] fp32 -> whi/wlo bf16 (same [o][c] layout, hi/lo split)
__global__ __launch_bounds__(256) void cast_w(const float* __restrict__ w,
                                              u16* __restrict__ whi,
                                              u16* __restrict__ wlo) {
    int i = blockIdx.x * 256 + threadIdx.x;
    if (i >= COUT_ * 2 * C_) return;
    float v = w[i];
    u16 h = f2bf(v);
    whi[i] = h;
    wlo[i] = f2bf(v - bf2f(h));
}

// K1c: global max of norm2 — multi-block; norm2>=0 -> int-bits atomicMax.
__global__ __launch_bounds__(256) void norm_max(const float* __restrict__ norm2,
                                                int* __restrict__ maxbits) {
    const int tid = blockIdx.x * 256 + threadIdx.x;
    float m = 0.0f;
    for (int i = tid; i < NTOK_; i += gridDim.x * 256) m = fmaxf(m, norm2[i]);
#pragma unroll
    for (int d = 1; d < 64; d <<= 1) m = fmaxf(m, __shfl_xor(m, d));
    if ((threadIdx.x & 63) == 0) atomicMax(maxbits, __float_as_int(m));
}

// ---------------------------------------------------------------------------
// K2: MFMA flash attention, transposed-S, 4-way split-K.
// R21: PIPE-SPLIT. R19 (all-LDS) saturates LDS (~287KB/CU/period vs 85B/cy
// ceiling => 3380cy > 3133 period); R20 (K-direct) saturated VMEM instead
// (144KB/CU/period at ~64B/cy + L2 latency in the MFMA chain) = 117us.
// Split: Kh+V via LDS DMA (188KB/CU/period ~ 2210cy), Kl direct from
// fragment-major global (72KB/CU/period ~ 1150cy) — both under ceiling.
// Fragment-major Kh staging: DMA source contiguous 6x1KB AND LDS reads
// sequential lane*16 => conflict-free by construction.
// Math bit-identical to R19/R20 -> absmax must stay 0.03125.
__global__ __launch_bounds__(256, 3) void flash_attn_mfma32(const u16* __restrict__ xf_hi,
                                                            const u16* __restrict__ xf_lo,
                                                            const u16* __restrict__ xc_hi,
                                                            const float* __restrict__ norm2,
                                                            const int* __restrict__ maxbits,
                                                            float* __restrict__ attT,
                                                            float* __restrict__ l_arr) {
    __shared__ __align__(16) char LDSU[2][K2_BUFSZ];
    const int b     = blockIdx.y;
    const int i0    = blockIdx.x * 128;
    const int split = blockIdx.z;
    const int kt0   = (NT98 * split) / NSPLIT;
    const int kt1   = (NT98 * (split + 1)) / NSPLIT;
    const int tid   = threadIdx.x;
    const int lane  = tid & 63;
    const int w     = tid >> 6;
    const int col   = lane & 31;
    const int g     = lane >> 5;

    const u16* fh = xf_hi + ((size_t)b * NT98 * 6 << 9);
    const u16* fl = xf_lo + ((size_t)b * NT98 * 6 << 9);
    const u16* vh = xc_hi + (size_t)b * C_ * N_;

    // 14 DMA slots of 1KB per buffer: Kh 0..5 (contiguous from xf_hi),
    // V 6..13 (80B-row pattern from xc_hi — verified R16/R20).
    // Wave w owns slots w+4j.
    u32 loff[4], dofs[4];
#pragma unroll
    for (int j = 0; j < 4; j++) {
        int s = w + 4 * j;
        if (s >= 14) { loff[j] = 0; dofs[j] = 0; continue; }
        if (s < 6) {                  // Kh: contiguous 1KB slots
            loff[j] = (u32)(s * 1024 + lane * 16);
            dofs[j] = (u32)(s * 1024);
        } else {                      // V
            int t = s - 6;
            int p = t * 64 + lane;    // 16B chunk 0..511 (480 data + pad)
            int ch = p / 5, c = p % 5;
            if (c > 3) c = 3;
            loff[j] = (ch < 96) ? (u32)(ch * (N_ * 2) + c * 16) : 0u;
            dofs[j] = (u32)(K2_V_OFF + t * 1024);
        }
    }

    // Q frags: coalesced dwordx4 from fragment-major arrays, once
    int qt = blockIdx.x * 4 + w;
    if (qt > NT98 - 1) qt = NT98 - 1;
    const int qrow  = i0 + w * 32 + col;
    const int qrowc = qrow < N_ ? qrow : N_ - 1;
    short8 qh[6], ql[6];
#pragma unroll
    for (int kc = 0; kc < 6; kc++) {
        qh[kc] = *(const short8*)&fh[foff(qt, kc) + lane * 8];
        ql[kc] = *(const short8*)&fl[foff(qt, kc) + lane * 8];
    }
    const float maxn2 = __int_as_float(*maxbits);
    const float m_i   = sqrtf(norm2[(size_t)b * N_ + qrowc] * maxn2);
    float l_acc = 0.0f;
    f32x16 O0 = {0}, O1 = {0}, O2 = {0};

    // stage tile kt (Kh + V) into buffer nbuf (async DMA)
    auto stage = [&](int nbuf, int kt) {
        const u32 ktK = (u32)kt * 6144u;   // Kh: 6KB contiguous per tile
        const u32 ktV = (u32)kt * 64u;     // V: 32 tokens * 2B
#pragma unroll
        for (int j = 0; j < 4; j++) {
            int s = w + 4 * j;
            if (s >= 14) break;
            const char* sb = (s < 6) ? (const char*)fh + ktK
                                     : (const char*)vh + ktV;
            gload_lds16(sb + loff[j], (char*)&LDSU[nbuf][0] + dofs[j]);
        }
    };

    stage(0, kt0);
    __syncthreads();

    const int g16 = g * 16;
    int buf = 0;
    for (int kt = kt0; kt < kt1; kt++) {
        // (1) prefetch next tile into back buffer
        if (kt + 1 < kt1) stage(buf ^ 1, kt + 1);

        const char* Lb = (const char*)&LDSU[buf][0];

        // (2) Kl frags direct from global (coalesced, L1-hot) — issued
        //     before the MFMA chain so latency hides under Kh/QK work.
        short8 kl[6];
#pragma unroll
        for (int kc = 0; kc < 6; kc++)
            kl[kc] = *(const short8*)&fl[foff(kt, kc) + lane * 8];

        // (3) QK^T: Kh from LDS (sequential lane*16 — conflict-free)
        f32x16 S = {0};
        __builtin_amdgcn_s_setprio(1);
#pragma unroll
        for (int kc = 0; kc < 6; kc++) {
            short8 kh = *(const short8*)(Lb + kc * 1024 + lane * 16);
            S = __builtin_amdgcn_mfma_f32_32x32x16_bf16(kh, ql[kc], S, 0, 0, 0);
            S = __builtin_amdgcn_mfma_f32_32x32x16_bf16(kl[kc], qh[kc], S, 0, 0, 0);
            S = __builtin_amdgcn_mfma_f32_32x32x16_bf16(kh, qh[kc], S, 0, 0, 0);
        }
        __builtin_amdgcn_s_setprio(0);

        // (4) softmax numerators + bf16 pack
        float p[16];
#pragma unroll
        for (int r = 0; r < 16; r++) {
            p[r] = __expf(S[r] - m_i);
            l_acc += p[r];
        }
        u32 w8[8];
#pragma unroll
        for (int q = 0; q < 8; q++) w8[q] = packbf2(p[2 * q], p[2 * q + 1]);

        // (5) PV from V-LDS (80B rows: conflict-free)
        __builtin_amdgcn_s_setprio(1);
#pragma unroll
        for (int kc = 0; kc < 2; kc++) {
            const int qb = kc * 4;
            u32 a0 = w8[qb + 0], a1 = w8[qb + 1];
            u32 a2 = w8[qb + 2], a3 = w8[qb + 3];
            u32 s0 = __shfl_xor((int)a0, 32), s1 = __shfl_xor((int)a1, 32);
            u32 s2 = __shfl_xor((int)a2, 32), s3 = __shfl_xor((int)a3, 32);
            union { short8 v; u32 u[4]; } Bf;
            Bf.u[0] = g ? s2 : a0;
            Bf.u[1] = g ? s3 : a1;
            Bf.u[2] = g ? a2 : s0;
            Bf.u[3] = g ? a3 : s1;
            const int vo = K2_V_OFF + col * 80 + kc * 32 + g16;
            short8 v0 = *(const short8*)(Lb + vo);
            short8 v1 = *(const short8*)(Lb + vo + 2560);   // +32 ch
            short8 v2 = *(const short8*)(Lb + vo + 5120);   // +64 ch
            O0 = __builtin_amdgcn_mfma_f32_32x32x16_bf16(v0, Bf.v, O0, 0, 0, 0);
            O1 = __builtin_amdgcn_mfma_f32_32x32x16_bf16(v1, Bf.v, O1, 0, 0, 0);
            O2 = __builtin_amdgcn_mfma_f32_32x32x16_bf16(v2, Bf.v, O2, 0, 0, 0);
        }
        __builtin_amdgcn_s_setprio(0);

        __syncthreads();     // drains my DMAs + all waves' LDS reads done
        buf ^= 1;
    }

    if (qrow < N_) {
        float* ab = attT + (size_t)b * C_ * N_ + qrow;
#pragma unroll
        for (int r = 0; r < 16; r++) {
            int c = (r & 3) + 8 * (r >> 2) + 4 * g;
            atomicAdd(&ab[(size_t)(c)      * N_], O0[r]);
            atomicAdd(&ab[(size_t)(c + 32) * N_], O1[r]);
            atomicAdd(&ab[(size_t)(c + 64) * N_], O2[r]);
        }
        float l_tot = l_acc + __shfl_xor(l_acc, 32);
        if (g == 0) atomicAdd(&l_arr[(size_t)b * N_ + qrow], l_tot);
    }
}

// ---------------------------------------------------------------------------
// K3: MFMA 1x1 conv (R17 32-token/128-thread version; unchanged)
__global__ __launch_bounds__(128, 3) void conv_mfma(const float* __restrict__ x,
                                                    const float* __restrict__ attT,
                                                    const float* __restrict__ l_arr,
                                                    const u16* __restrict__ whi,
                                                    const u16* __restrict__ wlo,
                                                    const float* __restrict__ convb,
                                                    float* __restrict__ y) {
    __shared__ u16 ch[32 * CROW];
    __shared__ u16 cl[32 * CROW];
    __shared__ float invl[32];
    const int b   = blockIdx.x / (N_ / 32);
    const int n0  = (blockIdx.x % (N_ / 32)) * 32;
    const int tid = threadIdx.x;

    if (tid < 32) invl[tid] = 1.0f / l_arr[(size_t)b * N_ + n0 + tid];
    __syncthreads();

    const float* xb = x    + (size_t)b * C_ * N_ + n0;
    const float* ab = attT + (size_t)b * C_ * N_ + n0;
    for (int e = tid; e < 32 * C_; e += 128) {
        int c = e >> 5, t = e & 31;
        float xv = xb[(size_t)c * N_ + t];
        float au = ab[(size_t)c * N_ + t];
        float xj = fmaxf(xv - au * invl[t], 0.0f);
        u16 h1 = f2bf(xv);
        ch[t * CROW + c] = h1;
        cl[t * CROW + c] = f2bf(xv - bf2f(h1));
        u16 h2 = f2bf(xj);
        ch[t * CROW + C_ + c] = h2;
        cl[t * CROW + C_ + c] = f2bf(xj - bf2f(h2));
    }
    __syncthreads();

    const int lane = tid & 63;
    const int w    = tid >> 6;        // 0..1
    const int col  = lane & 31;       // token within tile
    const int g    = lane >> 5;
    const int m0   = w * 3;           // wave's 3 m-tiles (96 channels)

    f32x16 A[3] = {{0}, {0}, {0}};
#pragma unroll
    for (int ks = 0; ks < 12; ks++) {
        const int k0 = ks * 16;
        short8 bh = *(const short8*)&ch[col * CROW + k0 + g * 8];
        short8 bl = *(const short8*)&cl[col * CROW + k0 + g * 8];
#pragma unroll
        for (int mt = 0; mt < 3; mt++) {
            const size_t wo = (size_t)((m0 + mt) * 32 + col) * (2 * C_) + k0 + g * 8;
            short8 ah = *(const short8*)&whi[wo];
            short8 al = *(const short8*)&wlo[wo];
            A[mt] = __builtin_amdgcn_mfma_f32_32x32x16_bf16(ah, bl, A[mt], 0, 0, 0);
            A[mt] = __builtin_amdgcn_mfma_f32_32x32x16_bf16(al, bh, A[mt], 0, 0, 0);
            A[mt] = __builtin_amdgcn_mfma_f32_32x32x16_bf16(ah, bh, A[mt], 0, 0, 0);
        }
    }

    float* yb = y + (size_t)b * COUT_ * N_ + n0 + col;
#pragma unroll
    for (int mt = 0; mt < 3; mt++)
#pragma unroll
        for (int r = 0; r < 16; r++) {
            int o = (m0 + mt) * 32 + (r & 3) + 8 * (r >> 2) + 4 * g;
            yb[(size_t)o * N_] = A[mt][r] + convb[o];
        }
}

// ---------------------------------------------------------------------------
// K4a: per-(b,channel) partial BN sums (distinct output lines, no contention)
__global__ __launch_bounds__(256) void bn_partial(const float* __restrict__ y,
                                                  float* __restrict__ pb) {
    const int o   = blockIdx.x;
    const int b   = blockIdx.y;
    const int tid = threadIdx.x;
    float s = 0.0f, q = 0.0f;
    const float4* p = (const float4*)(y + (size_t)(b * COUT_ + o) * N_);
    for (int i = tid; i < N_ / 4; i += 256) {
        float4 v = p[i];
        s += v.x + v.y + v.z + v.w;
        q += v.x * v.x + v.y * v.y + v.z * v.z + v.w * v.w;
    }
#pragma unroll
    for (int d = 1; d < 64; d <<= 1) {
        s += __shfl_xor(s, d);
        q += __shfl_xor(q, d);
    }
    __shared__ float wss[4], wqq[4];
    if ((tid & 63) == 0) { wss[tid >> 6] = s; wqq[tid >> 6] = q; }
    __syncthreads();
    if (tid == 0) {
        pb[b * COUT_ + o]                = wss[0] + wss[1] + wss[2] + wss[3];
        pb[B_ * COUT_ + b * COUT_ + o]   = wqq[0] + wqq[1] + wqq[2] + wqq[3];
    }
}

// K4b: reduce partials -> scale/shift
__global__ __launch_bounds__(192) void bn_finish(const float* __restrict__ pb,
                                                 const float* __restrict__ gamma,
                                                 const float* __restrict__ beta,
                                                 float* __restrict__ ss) {
    const int o = threadIdx.x;
    float s = 0.0f, q = 0.0f;
#pragma unroll
    for (int b = 0; b < B_; b++) {
        s += pb[b * COUT_ + o];
        q += pb[B_ * COUT_ + b * COUT_ + o];
    }
    const float invn = 1.0f / (float)NTOK_;
    float mean = s * invn;
    float var  = q * invn - mean * mean;
    float sc   = gamma[o] * rsqrtf(var + BN_EPS);
    ss[o]         = sc;
    ss[COUT_ + o] = beta[o] - mean * sc;
}

// K5: y -> BN affine -> exact GELU -> fp32 out
__global__ __launch_bounds__(256) void bn_gelu_out(const float* __restrict__ y,
                                                   const float* __restrict__ ss,
                                                   float* __restrict__ out) {
    const int total4 = (B_ * COUT_ * N_) / 4;
    int i = blockIdx.x * 256 + threadIdx.x;
    if (i >= total4) return;
    int base = i * 4;
    int o = (base / N_) % COUT_;
    float sc = ss[o], sh = ss[COUT_ + o];
    float4 v = *(const float4*)&y[base];
    float u0 = fmaf(v.x, sc, sh), u1 = fmaf(v.y, sc, sh);
    float u2 = fmaf(v.z, sc, sh), u3 = fmaf(v.w, sc, sh);
    const float k = 0.70710678118654752f;
    float4 g;
    g.x = 0.5f * u0 * (1.0f + erff(u0 * k));
    g.y = 0.5f * u1 * (1.0f + erff(u1 * k));
    g.z = 0.5f * u2 * (1.0f + erff(u2 * k));
    g.w = 0.5f * u3 * (1.0f + erff(u3 * k));
    *(float4*)&out[base] = g;
}

// ---------------------------------------------------------------------------
extern "C" void kernel_launch(void* const* d_in, const int* in_sizes, int n_in,
                              void* d_out, int out_size, void* d_ws, size_t ws_size,
                              hipStream_t stream) {
    const float* x     = (const float*)d_in[0];
    const float* w     = (const float*)d_in[1];
    const float* cb    = (const float*)d_in[2];
    const float* gamma = (const float*)d_in[3];
    const float* beta  = (const float*)d_in[4];

    u16* xf_hi = (u16*)d_ws;                         // BNC bf16 (fragment-major)
    u16* xf_lo = xf_hi + (size_t)BNC;                // BNC
    u16* xc_hi = xf_lo + (size_t)BNC;                // BNC (channel-major, V)
    float* attT  = (float*)(xc_hi + (size_t)BNC);    // BNC fp32
    u16* whi   = (u16*)(attT + (size_t)BNC);         // 192*192 bf16
    u16* wlo   = whi + COUT_ * 2 * C_;               // 192*192 bf16
    float* y     = (float*)(wlo + COUT_ * 2 * C_);   // B*COUT*N fp32
    float* ss    = y + (size_t)B_ * COUT_ * N_;      // 2*COUT
    float* l_arr = ss + 2 * COUT_;                   // NTOK
    float* norm2 = l_arr + NTOK_;                    // NTOK
    int*   maxb  = (int*)(norm2 + NTOK_);            // 1
    float* pb    = attT;                             // 2*B*COUT partials (attT dead after conv)

    hipMemsetAsync(l_arr, 0, NTOK_ * sizeof(float), stream);
    hipMemsetAsync(norm2, 0, NTOK_ * sizeof(float), stream);
    hipMemsetAsync(maxb, 0, sizeof(int), stream);
    hipMemsetAsync(attT, 0, (size_t)BNC * sizeof(float), stream);

    transpose_split<<<dim3(N_ / 32, C_ / 32, B_), 256, 0, stream>>>(x, xf_hi, xf_lo, xc_hi, norm2);
    cast_w<<<dim3((COUT_ * 2 * C_ + 255) / 256), 256, 0, stream>>>(w, whi, wlo);
    norm_max<<<dim3(25), 256, 0, stream>>>(norm2, maxb);
    flash_attn_mfma32<<<dim3((N_ + 127) / 128, B_, NSPLIT), 256, 0, stream>>>(
        xf_hi, xf_lo, xc_hi, norm2, maxb, attT, l_arr);
    conv_mfma<<<dim3(B_ * (N_ / 32)), 128, 0, stream>>>(x, attT, l_arr, whi, wlo, cb, y);
    bn_partial<<<dim3(COUT_, B_), 256, 0, stream>>>(y, pb);
    bn_finish<<<dim3(1), 192, 0, stream>>>(pb, gamma, beta, ss);
    bn_gelu_out<<<dim3((B_ * COUT_ * N_ / 4 + 255) / 256), 256, 0, stream>>>(y, ss, (float*)d_out);
}

// Round 11
// 216.144 us; speedup vs baseline: 1.1214x; 1.0773x over previous
//
#include <hip/hip_runtime.h>
#include <hip/hip_bf16.h>

// Problem constants
#define B_    8
#define C_    96
#define N_    3136      // 56*56
#define COUT_ 192
#define NTOK_ 25088     // B_*N_
#define BN_EPS 1e-5f

#define CROW 200        // conv cat LDS token-row stride in bf16 (192+8): 400B odd*16 -> conflict-free
#define BNC  (B_ * N_ * C_)
// R22: NSPLIT 4->3. 25*8*4=800 blocks > 768 resident slots (256CU x 3 blk)
// -> 32-block tail ran a FULL second block-duration with 224 CUs idle
// (occ 20% measured == (37.5%+2%)/2, the smoking gun). 600 blocks fit in
// ONE residency wave: ~49 -> ~33 tile-periods of wall-clock.
#define NSPLIT 3
#define NT98  98        // 32-row K tiles per batch (3136/32)

// K2 LDS per buffer: Kh frags 6KB (frag kc at kc*1024, lane*16 within) |
// V 8KB at +6144 (96 ch x 80B rows + pad). x2 buffers = 28672 B.
#define K2_V_OFF 6144
#define K2_BUFSZ 14336

typedef __hip_bfloat16 bf16;
typedef unsigned short u16;
typedef unsigned int u32;
typedef __attribute__((ext_vector_type(8))) short short8;    // 8 bf16 = 16B (MFMA A/B frag)
typedef __attribute__((ext_vector_type(16))) float f32x16;   // 32x32 MFMA C/D frag

__device__ __forceinline__ u16 f2bf(float f) {
    union { __hip_bfloat16 h; u16 u; } cv;
    cv.h = __float2bfloat16(f);
    return cv.u;
}
__device__ __forceinline__ float bf2f(u16 v) {
    union { u16 u; __hip_bfloat16 h; } cv;
    cv.u = v;
    return __bfloat162float(cv.h);
}
__device__ __forceinline__ u32 packbf2(float lo, float hi) {
    return ((u32)f2bf(hi) << 16) | (u32)f2bf(lo);
}

// async global->LDS DMA, 16B per lane: LDS dest = WAVE-UNIFORM base + lane*16.
__device__ __forceinline__ void gload_lds16(const void* g, void* l) {
    __builtin_amdgcn_global_load_lds((const __attribute__((address_space(1))) void*)g,
                                     (__attribute__((address_space(3))) void*)l,
                                     16, 0, 0);
}

// fragment offset in xf arrays: frag (b-pre-offset pointer, tile t, chunk kc)
// = ((t*6)+kc) * 512 u16 (1KB). Lane l holds token t*32+(l&31),
// channels kc*16+(l>>5)*8 .. +8 — exactly the mfma_32x32x16 A/B layout.
__device__ __forceinline__ size_t foff(int t, int kc) {
    return ((size_t)t * 6 + kc) << 9;
}

// ---------------------------------------------------------------------------
// K1: x [B][C][N] fp32 ->
//   xf_hi/xf_lo [B][98][6][512] bf16 fragment-major (K and Q frags, hi/lo)
//   xc_hi [B][C][N] bf16 (channel-major, V staged from here)
//   norm2 per-token squared norms.  (R20 version — HW-verified correct.)
__global__ __launch_bounds__(256) void transpose_split(const float* __restrict__ x,
                                                       u16* __restrict__ xf_hi,
                                                       u16* __restrict__ xf_lo,
                                                       u16* __restrict__ xc_hi,
                                                       float* __restrict__ norm2) {
    __shared__ float tile[32][33];
    __shared__ float nrm[32];
    const int nb = blockIdx.x * 32;     // token base (tile t = nb/32)
    const int cb = blockIdx.y * 32;     // channel base (kc = cb/16 + {0,1})
    const int b  = blockIdx.z;
    const int tid = threadIdx.x;
    const int tx = tid & 31;
    const int ty = tid >> 5;
    if (tid < 32) nrm[tid] = 0.0f;
    float psum = 0.0f;
#pragma unroll
    for (int r = 0; r < 32; r += 8) {
        size_t idx = ((size_t)b * C_ + cb + ty + r) * N_ + nb + tx;
        float v = x[idx];
        tile[ty + r][tx] = v;
        xc_hi[idx] = f2bf(v);
        psum = fmaf(v, v, psum);
    }
    __syncthreads();               // tile visible; nrm init done
    atomicAdd(&nrm[tx], psum);     // LDS atomic, 8 adders per slot

    // phase 2: fragment-major hi/lo writes. 128 items (kc_i in 0..1, lane l
    // in 0..63); threads 0-127 write hi, 128-255 write lo. 16B/thread.
    {
        const int item  = tid & 127;
        const int is_lo = tid >> 7;
        const int kc_i  = item >> 6;
        const int l     = item & 63;
        const int kcg   = (cb >> 4) + kc_i;
        union { u16 a[8]; short8 v8; } o;
#pragma unroll
        for (int j = 0; j < 8; j++) {
            float v = tile[kc_i * 16 + ((l >> 5) * 8) + j][l & 31];
            u16 h = f2bf(v);
            o.a[j] = is_lo ? f2bf(v - bf2f(h)) : h;
        }
        u16* dst = (is_lo ? xf_lo : xf_hi) +
                   ((size_t)b * NT98 * 6 << 9) + foff(nb >> 5, kcg) + l * 8;
        *(short8*)dst = o.v8;
    }
    __syncthreads();               // nrm complete
    if (tid < 32)
        atomicAdd(&norm2[(size_t)b * N_ + nb + tid], nrm[tid]);
}

// K1b: conv_w [O][2C] fp32 -> whi/wlo bf16 (same [o][c] layout, hi/lo split)
__global__ __launch_bounds__(256) void cast_w(const float* __restrict__ w,
                                              u16* __restrict__ whi,
                                              u16* __restrict__ wlo) {
    int i = blockIdx.x * 256 + threadIdx.x;
    if (i >= COUT_ * 2 * C_) return;
    float v = w[i];
    u16 h = f2bf(v);
    whi[i] = h;
    wlo[i] = f2bf(v - bf2f(h));
}

// K1c: global max of norm2 — multi-block; norm2>=0 -> int-bits atomicMax.
__global__ __launch_bounds__(256) void norm_max(const float* __restrict__ norm2,
                                                int* __restrict__ maxbits) {
    const int tid = blockIdx.x * 256 + threadIdx.x;
    float m = 0.0f;
    for (int i = tid; i < NTOK_; i += gridDim.x * 256) m = fmaxf(m, norm2[i]);
#pragma unroll
    for (int d = 1; d < 64; d <<= 1) m = fmaxf(m, __shfl_xor(m, d));
    if ((threadIdx.x & 63) == 0) atomicMax(maxbits, __float_as_int(m));
}

// ---------------------------------------------------------------------------
// K2: MFMA flash attention, transposed-S, 3-way split-K.
// Body = R21 (pipe-split: Kh+V via LDS DMA, Kl direct from fragment-major
// global; conflicts 0; bit-identical math). R22 changes ONLY NSPLIT (grid
// 800->600 blocks) to eliminate the full-length 32-block residency tail.
__global__ __launch_bounds__(256, 3) void flash_attn_mfma32(const u16* __restrict__ xf_hi,
                                                            const u16* __restrict__ xf_lo,
                                                            const u16* __restrict__ xc_hi,
                                                            const float* __restrict__ norm2,
                                                            const int* __restrict__ maxbits,
                                                            float* __restrict__ attT,
                                                            float* __restrict__ l_arr) {
    __shared__ __align__(16) char LDSU[2][K2_BUFSZ];
    const int b     = blockIdx.y;
    const int i0    = blockIdx.x * 128;
    const int split = blockIdx.z;
    const int kt0   = (NT98 * split) / NSPLIT;
    const int kt1   = (NT98 * (split + 1)) / NSPLIT;
    const int tid   = threadIdx.x;
    const int lane  = tid & 63;
    const int w     = tid >> 6;
    const int col   = lane & 31;
    const int g     = lane >> 5;

    const u16* fh = xf_hi + ((size_t)b * NT98 * 6 << 9);
    const u16* fl = xf_lo + ((size_t)b * NT98 * 6 << 9);
    const u16* vh = xc_hi + (size_t)b * C_ * N_;

    // 14 DMA slots of 1KB per buffer: Kh 0..5 (contiguous from xf_hi),
    // V 6..13 (80B-row pattern from xc_hi — verified R16/R20).
    // Wave w owns slots w+4j.
    u32 loff[4], dofs[4];
#pragma unroll
    for (int j = 0; j < 4; j++) {
        int s = w + 4 * j;
        if (s >= 14) { loff[j] = 0; dofs[j] = 0; continue; }
        if (s < 6) {                  // Kh: contiguous 1KB slots
            loff[j] = (u32)(s * 1024 + lane * 16);
            dofs[j] = (u32)(s * 1024);
        } else {                      // V
            int t = s - 6;
            int p = t * 64 + lane;    // 16B chunk 0..511 (480 data + pad)
            int ch = p / 5, c = p % 5;
            if (c > 3) c = 3;
            loff[j] = (ch < 96) ? (u32)(ch * (N_ * 2) + c * 16) : 0u;
            dofs[j] = (u32)(K2_V_OFF + t * 1024);
        }
    }

    // Q frags: coalesced dwordx4 from fragment-major arrays, once
    int qt = blockIdx.x * 4 + w;
    if (qt > NT98 - 1) qt = NT98 - 1;
    const int qrow  = i0 + w * 32 + col;
    const int qrowc = qrow < N_ ? qrow : N_ - 1;
    short8 qh[6], ql[6];
#pragma unroll
    for (int kc = 0; kc < 6; kc++) {
        qh[kc] = *(const short8*)&fh[foff(qt, kc) + lane * 8];
        ql[kc] = *(const short8*)&fl[foff(qt, kc) + lane * 8];
    }
    const float maxn2 = __int_as_float(*maxbits);
    const float m_i   = sqrtf(norm2[(size_t)b * N_ + qrowc] * maxn2);
    float l_acc = 0.0f;
    f32x16 O0 = {0}, O1 = {0}, O2 = {0};

    // stage tile kt (Kh + V) into buffer nbuf (async DMA)
    auto stage = [&](int nbuf, int kt) {
        const u32 ktK = (u32)kt * 6144u;   // Kh: 6KB contiguous per tile
        const u32 ktV = (u32)kt * 64u;     // V: 32 tokens * 2B
#pragma unroll
        for (int j = 0; j < 4; j++) {
            int s = w + 4 * j;
            if (s >= 14) break;
            const char* sb = (s < 6) ? (const char*)fh + ktK
                                     : (const char*)vh + ktV;
            gload_lds16(sb + loff[j], (char*)&LDSU[nbuf][0] + dofs[j]);
        }
    };

    stage(0, kt0);
    __syncthreads();

    const int g16 = g * 16;
    int buf = 0;
    for (int kt = kt0; kt < kt1; kt++) {
        // (1) prefetch next tile into back buffer
        if (kt + 1 < kt1) stage(buf ^ 1, kt + 1);

        const char* Lb = (const char*)&LDSU[buf][0];

        // (2) Kl frags direct from global (coalesced, L1-hot) — issued
        //     before the MFMA chain so latency hides under Kh/QK work.
        short8 kl[6];
#pragma unroll
        for (int kc = 0; kc < 6; kc++)
            kl[kc] = *(const short8*)&fl[foff(kt, kc) + lane * 8];

        // (3) QK^T: Kh from LDS (sequential lane*16 — conflict-free)
        f32x16 S = {0};
        __builtin_amdgcn_s_setprio(1);
#pragma unroll
        for (int kc = 0; kc < 6; kc++) {
            short8 kh = *(const short8*)(Lb + kc * 1024 + lane * 16);
            S = __builtin_amdgcn_mfma_f32_32x32x16_bf16(kh, ql[kc], S, 0, 0, 0);
            S = __builtin_amdgcn_mfma_f32_32x32x16_bf16(kl[kc], qh[kc], S, 0, 0, 0);
            S = __builtin_amdgcn_mfma_f32_32x32x16_bf16(kh, qh[kc], S, 0, 0, 0);
        }
        __builtin_amdgcn_s_setprio(0);

        // (4) softmax numerators + bf16 pack
        float p[16];
#pragma unroll
        for (int r = 0; r < 16; r++) {
            p[r] = __expf(S[r] - m_i);
            l_acc += p[r];
        }
        u32 w8[8];
#pragma unroll
        for (int q = 0; q < 8; q++) w8[q] = packbf2(p[2 * q], p[2 * q + 1]);

        // (5) PV from V-LDS (80B rows: conflict-free)
        __builtin_amdgcn_s_setprio(1);
#pragma unroll
        for (int kc = 0; kc < 2; kc++) {
            const int qb = kc * 4;
            u32 a0 = w8[qb + 0], a1 = w8[qb + 1];
            u32 a2 = w8[qb + 2], a3 = w8[qb + 3];
            u32 s0 = __shfl_xor((int)a0, 32), s1 = __shfl_xor((int)a1, 32);
            u32 s2 = __shfl_xor((int)a2, 32), s3 = __shfl_xor((int)a3, 32);
            union { short8 v; u32 u[4]; } Bf;
            Bf.u[0] = g ? s2 : a0;
            Bf.u[1] = g ? s3 : a1;
            Bf.u[2] = g ? a2 : s0;
            Bf.u[3] = g ? a3 : s1;
            const int vo = K2_V_OFF + col * 80 + kc * 32 + g16;
            short8 v0 = *(const short8*)(Lb + vo);
            short8 v1 = *(const short8*)(Lb + vo + 2560);   // +32 ch
            short8 v2 = *(const short8*)(Lb + vo + 5120);   // +64 ch
            O0 = __builtin_amdgcn_mfma_f32_32x32x16_bf16(v0, Bf.v, O0, 0, 0, 0);
            O1 = __builtin_amdgcn_mfma_f32_32x32x16_bf16(v1, Bf.v, O1, 0, 0, 0);
            O2 = __builtin_amdgcn_mfma_f32_32x32x16_bf16(v2, Bf.v, O2, 0, 0, 0);
        }
        __builtin_amdgcn_s_setprio(0);

        __syncthreads();     // drains my DMAs + all waves' LDS reads done
        buf ^= 1;
    }

    if (qrow < N_) {
        float* ab = attT + (size_t)b * C_ * N_ + qrow;
#pragma unroll
        for (int r = 0; r < 16; r++) {
            int c = (r & 3) + 8 * (r >> 2) + 4 * g;
            atomicAdd(&ab[(size_t)(c)      * N_], O0[r]);
            atomicAdd(&ab[(size_t)(c + 32) * N_], O1[r]);
            atomicAdd(&ab[(size_t)(c + 64) * N_], O2[r]);
        }
        float l_tot = l_acc + __shfl_xor(l_acc, 32);
        if (g == 0) atomicAdd(&l_arr[(size_t)b * N_ + qrow], l_tot);
    }
}

// ---------------------------------------------------------------------------
// K3: MFMA 1x1 conv (R17 32-token/128-thread version; unchanged)
__global__ __launch_bounds__(128, 3) void conv_mfma(const float* __restrict__ x,
                                                    const float* __restrict__ attT,
                                                    const float* __restrict__ l_arr,
                                                    const u16* __restrict__ whi,
                                                    const u16* __restrict__ wlo,
                                                    const float* __restrict__ convb,
                                                    float* __restrict__ y) {
    __shared__ u16 ch[32 * CROW];
    __shared__ u16 cl[32 * CROW];
    __shared__ float invl[32];
    const int b   = blockIdx.x / (N_ / 32);
    const int n0  = (blockIdx.x % (N_ / 32)) * 32;
    const int tid = threadIdx.x;

    if (tid < 32) invl[tid] = 1.0f / l_arr[(size_t)b * N_ + n0 + tid];
    __syncthreads();

    const float* xb = x    + (size_t)b * C_ * N_ + n0;
    const float* ab = attT + (size_t)b * C_ * N_ + n0;
    for (int e = tid; e < 32 * C_; e += 128) {
        int c = e >> 5, t = e & 31;
        float xv = xb[(size_t)c * N_ + t];
        float au = ab[(size_t)c * N_ + t];
        float xj = fmaxf(xv - au * invl[t], 0.0f);
        u16 h1 = f2bf(xv);
        ch[t * CROW + c] = h1;
        cl[t * CROW + c] = f2bf(xv - bf2f(h1));
        u16 h2 = f2bf(xj);
        ch[t * CROW + C_ + c] = h2;
        cl[t * CROW + C_ + c] = f2bf(xj - bf2f(h2));
    }
    __syncthreads();

    const int lane = tid & 63;
    const int w    = tid >> 6;        // 0..1
    const int col  = lane & 31;       // token within tile
    const int g    = lane >> 5;
    const int m0   = w * 3;           // wave's 3 m-tiles (96 channels)

    f32x16 A[3] = {{0}, {0}, {0}};
#pragma unroll
    for (int ks = 0; ks < 12; ks++) {
        const int k0 = ks * 16;
        short8 bh = *(const short8*)&ch[col * CROW + k0 + g * 8];
        short8 bl = *(const short8*)&cl[col * CROW + k0 + g * 8];
#pragma unroll
        for (int mt = 0; mt < 3; mt++) {
            const size_t wo = (size_t)((m0 + mt) * 32 + col) * (2 * C_) + k0 + g * 8;
            short8 ah = *(const short8*)&whi[wo];
            short8 al = *(const short8*)&wlo[wo];
            A[mt] = __builtin_amdgcn_mfma_f32_32x32x16_bf16(ah, bl, A[mt], 0, 0, 0);
            A[mt] = __builtin_amdgcn_mfma_f32_32x32x16_bf16(al, bh, A[mt], 0, 0, 0);
            A[mt] = __builtin_amdgcn_mfma_f32_32x32x16_bf16(ah, bh, A[mt], 0, 0, 0);
        }
    }

    float* yb = y + (size_t)b * COUT_ * N_ + n0 + col;
#pragma unroll
    for (int mt = 0; mt < 3; mt++)
#pragma unroll
        for (int r = 0; r < 16; r++) {
            int o = (m0 + mt) * 32 + (r & 3) + 8 * (r >> 2) + 4 * g;
            yb[(size_t)o * N_] = A[mt][r] + convb[o];
        }
}

// ---------------------------------------------------------------------------
// K4a: per-(b,channel) partial BN sums (distinct output lines, no contention)
__global__ __launch_bounds__(256) void bn_partial(const float* __restrict__ y,
                                                  float* __restrict__ pb) {
    const int o   = blockIdx.x;
    const int b   = blockIdx.y;
    const int tid = threadIdx.x;
    float s = 0.0f, q = 0.0f;
    const float4* p = (const float4*)(y + (size_t)(b * COUT_ + o) * N_);
    for (int i = tid; i < N_ / 4; i += 256) {
        float4 v = p[i];
        s += v.x + v.y + v.z + v.w;
        q += v.x * v.x + v.y * v.y + v.z * v.z + v.w * v.w;
    }
#pragma unroll
    for (int d = 1; d < 64; d <<= 1) {
        s += __shfl_xor(s, d);
        q += __shfl_xor(q, d);
    }
    __shared__ float wss[4], wqq[4];
    if ((tid & 63) == 0) { wss[tid >> 6] = s; wqq[tid >> 6] = q; }
    __syncthreads();
    if (tid == 0) {
        pb[b * COUT_ + o]                = wss[0] + wss[1] + wss[2] + wss[3];
        pb[B_ * COUT_ + b * COUT_ + o]   = wqq[0] + wqq[1] + wqq[2] + wqq[3];
    }
}

// K4b: reduce partials -> scale/shift
__global__ __launch_bounds__(192) void bn_finish(const float* __restrict__ pb,
                                                 const float* __restrict__ gamma,
                                                 const float* __restrict__ beta,
                                                 float* __restrict__ ss) {
    const int o = threadIdx.x;
    float s = 0.0f, q = 0.0f;
#pragma unroll
    for (int b = 0; b < B_; b++) {
        s += pb[b * COUT_ + o];
        q += pb[B_ * COUT_ + b * COUT_ + o];
    }
    const float invn = 1.0f / (float)NTOK_;
    float mean = s * invn;
    float var  = q * invn - mean * mean;
    float sc   = gamma[o] * rsqrtf(var + BN_EPS);
    ss[o]         = sc;
    ss[COUT_ + o] = beta[o] - mean * sc;
}

// K5: y -> BN affine -> exact GELU -> fp32 out
__global__ __launch_bounds__(256) void bn_gelu_out(const float* __restrict__ y,
                                                   const float* __restrict__ ss,
                                                   float* __restrict__ out) {
    const int total4 = (B_ * COUT_ * N_) / 4;
    int i = blockIdx.x * 256 + threadIdx.x;
    if (i >= total4) return;
    int base = i * 4;
    int o = (base / N_) % COUT_;
    float sc = ss[o], sh = ss[COUT_ + o];
    float4 v = *(const float4*)&y[base];
    float u0 = fmaf(v.x, sc, sh), u1 = fmaf(v.y, sc, sh);
    float u2 = fmaf(v.z, sc, sh), u3 = fmaf(v.w, sc, sh);
    const float k = 0.70710678118654752f;
    float4 g;
    g.x = 0.5f * u0 * (1.0f + erff(u0 * k));
    g.y = 0.5f * u1 * (1.0f + erff(u1 * k));
    g.z = 0.5f * u2 * (1.0f + erff(u2 * k));
    g.w = 0.5f * u3 * (1.0f + erff(u3 * k));
    *(float4*)&out[base] = g;
}

// ---------------------------------------------------------------------------
extern "C" void kernel_launch(void* const* d_in, const int* in_sizes, int n_in,
                              void* d_out, int out_size, void* d_ws, size_t ws_size,
                              hipStream_t stream) {
    const float* x     = (const float*)d_in[0];
    const float* w     = (const float*)d_in[1];
    const float* cb    = (const float*)d_in[2];
    const float* gamma = (const float*)d_in[3];
    const float* beta  = (const float*)d_in[4];

    u16* xf_hi = (u16*)d_ws;                         // BNC bf16 (fragment-major)
    u16* xf_lo = xf_hi + (size_t)BNC;                // BNC
    u16* xc_hi = xf_lo + (size_t)BNC;                // BNC (channel-major, V)
    float* attT  = (float*)(xc_hi + (size_t)BNC);    // BNC fp32
    u16* whi   = (u16*)(attT + (size_t)BNC);         // 192*192 bf16
    u16* wlo   = whi + COUT_ * 2 * C_;               // 192*192 bf16
    float* y     = (float*)(wlo + COUT_ * 2 * C_);   // B*COUT*N fp32
    float* ss    = y + (size_t)B_ * COUT_ * N_;      // 2*COUT
    float* l_arr = ss + 2 * COUT_;                   // NTOK
    float* norm2 = l_arr + NTOK_;                    // NTOK
    int*   maxb  = (int*)(norm2 + NTOK_);            // 1
    float* pb    = attT;                             // 2*B*COUT partials (attT dead after conv)

    hipMemsetAsync(l_arr, 0, NTOK_ * sizeof(float), stream);
    hipMemsetAsync(norm2, 0, NTOK_ * sizeof(float), stream);
    hipMemsetAsync(maxb, 0, sizeof(int), stream);
    hipMemsetAsync(attT, 0, (size_t)BNC * sizeof(float), stream);

    transpose_split<<<dim3(N_ / 32, C_ / 32, B_), 256, 0, stream>>>(x, xf_hi, xf_lo, xc_hi, norm2);
    cast_w<<<dim3((COUT_ * 2 * C_ + 255) / 256), 256, 0, stream>>>(w, whi, wlo);
    norm_max<<<dim3(25), 256, 0, stream>>>(norm2, maxb);
    flash_attn_mfma32<<<dim3((N_ + 127) / 128, B_, NSPLIT), 256, 0, stream>>>(
        xf_hi, xf_lo, xc_hi, norm2, maxb, attT, l_arr);
    conv_mfma<<<dim3(B_ * (N_ / 32)), 128, 0, stream>>>(x, attT, l_arr, whi, wlo, cb, y);
    bn_partial<<<dim3(COUT_, B_), 256, 0, stream>>>(y, pb);
    bn_finish<<<dim3(1), 192, 0, stream>>>(pb, gamma, beta, ss);
    bn_gelu_out<<<dim3((B_ * COUT_ * N_ / 4 + 255) / 256), 256, 0, stream>>>(y, ss, (float*)d_out);
}

// Round 12
// 206.689 us; speedup vs baseline: 1.1727x; 1.0457x over previous
//
#include <hip/hip_runtime.h>
#include <hip/hip_bf16.h>

// Problem constants
#define B_    8
#define C_    96
#define N_    3136      // 56*56
#define COUT_ 192
#define NTOK_ 25088     // B_*N_
#define BN_EPS 1e-5f

#define CROW 200        // conv cat LDS token-row stride in bf16 (192+8): 400B odd*16 -> conflict-free
#define BNC  (B_ * N_ * C_)
#define NSPLIT 3
#define NT98  98        // 32-row K tiles per batch (3136/32)

// K2 LDS per buffer: Kh frags 6KB (frag kc at kc*1024, lane*16 within) |
// V 8KB at +6144 (96 ch x 80B rows + pad). x2 buffers = 28672 B.
#define K2_V_OFF 6144
#define K2_BUFSZ 14336

typedef __hip_bfloat16 bf16;
typedef unsigned short u16;
typedef unsigned int u32;
typedef __attribute__((ext_vector_type(8))) short short8;    // 8 bf16 = 16B (MFMA A/B frag)
typedef __attribute__((ext_vector_type(16))) float f32x16;   // 32x32 MFMA C/D frag

__device__ __forceinline__ u16 f2bf(float f) {
    union { __hip_bfloat16 h; u16 u; } cv;
    cv.h = __float2bfloat16(f);
    return cv.u;
}
__device__ __forceinline__ float bf2f(u16 v) {
    union { u16 u; __hip_bfloat16 h; } cv;
    cv.u = v;
    return __bfloat162float(cv.h);
}
__device__ __forceinline__ u32 packbf2(float lo, float hi) {
    return ((u32)f2bf(hi) << 16) | (u32)f2bf(lo);
}

// async global->LDS DMA, 16B per lane: LDS dest = WAVE-UNIFORM base + lane*16.
__device__ __forceinline__ void gload_lds16(const void* g, void* l) {
    __builtin_amdgcn_global_load_lds((const __attribute__((address_space(1))) void*)g,
                                     (__attribute__((address_space(3))) void*)l,
                                     16, 0, 0);
}

// fragment offset in xf arrays: frag (b-pre-offset pointer, tile t, chunk kc)
// = ((t*6)+kc) * 512 u16 (1KB). Lane l holds token t*32+(l&31),
// channels kc*16+(l>>5)*8 .. +8 — exactly the mfma_32x32x16 A/B layout.
__device__ __forceinline__ size_t foff(int t, int kc) {
    return ((size_t)t * 6 + kc) << 9;
}

// ---------------------------------------------------------------------------
// K1: x [B][C][N] fp32 ->
//   xf_hi/xf_lo [B][98][6][512] bf16 fragment-major (K and Q frags, hi/lo)
//   xc_hi [B][C][N] bf16 (channel-major, V staged from here)
//   norm2 per-token squared norms.  (R20 version — HW-verified correct.)
__global__ __launch_bounds__(256) void transpose_split(const float* __restrict__ x,
                                                       u16* __restrict__ xf_hi,
                                                       u16* __restrict__ xf_lo,
                                                       u16* __restrict__ xc_hi,
                                                       float* __restrict__ norm2) {
    __shared__ float tile[32][33];
    __shared__ float nrm[32];
    const int nb = blockIdx.x * 32;     // token base (tile t = nb/32)
    const int cb = blockIdx.y * 32;     // channel base (kc = cb/16 + {0,1})
    const int b  = blockIdx.z;
    const int tid = threadIdx.x;
    const int tx = tid & 31;
    const int ty = tid >> 5;
    if (tid < 32) nrm[tid] = 0.0f;
    float psum = 0.0f;
#pragma unroll
    for (int r = 0; r < 32; r += 8) {
        size_t idx = ((size_t)b * C_ + cb + ty + r) * N_ + nb + tx;
        float v = x[idx];
        tile[ty + r][tx] = v;
        xc_hi[idx] = f2bf(v);
        psum = fmaf(v, v, psum);
    }
    __syncthreads();               // tile visible; nrm init done
    atomicAdd(&nrm[tx], psum);     // LDS atomic, 8 adders per slot

    // phase 2: fragment-major hi/lo writes. 128 items (kc_i in 0..1, lane l
    // in 0..63); threads 0-127 write hi, 128-255 write lo. 16B/thread.
    {
        const int item  = tid & 127;
        const int is_lo = tid >> 7;
        const int kc_i  = item >> 6;
        const int l     = item & 63;
        const int kcg   = (cb >> 4) + kc_i;
        union { u16 a[8]; short8 v8; } o;
#pragma unroll
        for (int j = 0; j < 8; j++) {
            float v = tile[kc_i * 16 + ((l >> 5) * 8) + j][l & 31];
            u16 h = f2bf(v);
            o.a[j] = is_lo ? f2bf(v - bf2f(h)) : h;
        }
        u16* dst = (is_lo ? xf_lo : xf_hi) +
                   ((size_t)b * NT98 * 6 << 9) + foff(nb >> 5, kcg) + l * 8;
        *(short8*)dst = o.v8;
    }
    __syncthreads();               // nrm complete
    if (tid < 32)
        atomicAdd(&norm2[(size_t)b * N_ + nb + tid], nrm[tid]);
}

// K1b: conv_w [O][2C] fp32 -> wf_hi/wf_lo bf16 FRAGMENT-MAJOR.
// R23: frag (mt 0..5, ks 0..11) is 1KB at ((mt*12+ks)*512); lane l holds
// row mt*32+(l&31), chans ks*16+(l>>5)*8..+8 — the MFMA A-frag layout.
// Makes every conv weight load a single coalesced dwordx4 (was a 32-line
// gather). Same trick as R20/R21's xf arrays (HW-verified).
__global__ __launch_bounds__(256) void cast_w(const float* __restrict__ w,
                                              u16* __restrict__ wf_hi,
                                              u16* __restrict__ wf_lo) {
    int i = blockIdx.x * 256 + threadIdx.x;
    if (i >= COUT_ * 2 * C_) return;
    float v = w[i];
    u16 h  = f2bf(v);
    u16 lo = f2bf(v - bf2f(h));
    int o = i / (2 * C_), c = i % (2 * C_);
    int mt = o >> 5, lrow = o & 31;
    int ks = c >> 4, hi8 = (c >> 3) & 1, j = c & 7;
    size_t d = ((size_t)(mt * 12 + ks) * 64 + hi8 * 32 + lrow) * 8 + j;
    wf_hi[d] = h;
    wf_lo[d] = lo;
}

// K1c: global max of norm2 — multi-block; norm2>=0 -> int-bits atomicMax.
__global__ __launch_bounds__(256) void norm_max(const float* __restrict__ norm2,
                                                int* __restrict__ maxbits) {
    const int tid = blockIdx.x * 256 + threadIdx.x;
    float m = 0.0f;
    for (int i = tid; i < NTOK_; i += gridDim.x * 256) m = fmaxf(m, norm2[i]);
#pragma unroll
    for (int d = 1; d < 64; d <<= 1) m = fmaxf(m, __shfl_xor(m, d));
    if ((threadIdx.x & 63) == 0) atomicMax(maxbits, __float_as_int(m));
}

// ---------------------------------------------------------------------------
// K2: MFMA flash attention, transposed-S, 3-way split-K.
// FROZEN R22 body (90.5us, conflicts 0, occ-tail removed). Residual
// structure: 600-block imbalance (88 CUs x3 / 168 x2) + barrier sync;
// 98=2*7^2 has no 256-CU-aligned factorization -> on hold.
__global__ __launch_bounds__(256, 3) void flash_attn_mfma32(const u16* __restrict__ xf_hi,
                                                            const u16* __restrict__ xf_lo,
                                                            const u16* __restrict__ xc_hi,
                                                            const float* __restrict__ norm2,
                                                            const int* __restrict__ maxbits,
                                                            float* __restrict__ attT,
                                                            float* __restrict__ l_arr) {
    __shared__ __align__(16) char LDSU[2][K2_BUFSZ];
    const int b     = blockIdx.y;
    const int i0    = blockIdx.x * 128;
    const int split = blockIdx.z;
    const int kt0   = (NT98 * split) / NSPLIT;
    const int kt1   = (NT98 * (split + 1)) / NSPLIT;
    const int tid   = threadIdx.x;
    const int lane  = tid & 63;
    const int w     = tid >> 6;
    const int col   = lane & 31;
    const int g     = lane >> 5;

    const u16* fh = xf_hi + ((size_t)b * NT98 * 6 << 9);
    const u16* fl = xf_lo + ((size_t)b * NT98 * 6 << 9);
    const u16* vh = xc_hi + (size_t)b * C_ * N_;

    // 14 DMA slots of 1KB per buffer: Kh 0..5 (contiguous from xf_hi),
    // V 6..13 (80B-row pattern from xc_hi). Wave w owns slots w+4j.
    u32 loff[4], dofs[4];
#pragma unroll
    for (int j = 0; j < 4; j++) {
        int s = w + 4 * j;
        if (s >= 14) { loff[j] = 0; dofs[j] = 0; continue; }
        if (s < 6) {                  // Kh: contiguous 1KB slots
            loff[j] = (u32)(s * 1024 + lane * 16);
            dofs[j] = (u32)(s * 1024);
        } else {                      // V
            int t = s - 6;
            int p = t * 64 + lane;    // 16B chunk 0..511 (480 data + pad)
            int ch = p / 5, c = p % 5;
            if (c > 3) c = 3;
            loff[j] = (ch < 96) ? (u32)(ch * (N_ * 2) + c * 16) : 0u;
            dofs[j] = (u32)(K2_V_OFF + t * 1024);
        }
    }

    // Q frags: coalesced dwordx4 from fragment-major arrays, once
    int qt = blockIdx.x * 4 + w;
    if (qt > NT98 - 1) qt = NT98 - 1;
    const int qrow  = i0 + w * 32 + col;
    const int qrowc = qrow < N_ ? qrow : N_ - 1;
    short8 qh[6], ql[6];
#pragma unroll
    for (int kc = 0; kc < 6; kc++) {
        qh[kc] = *(const short8*)&fh[foff(qt, kc) + lane * 8];
        ql[kc] = *(const short8*)&fl[foff(qt, kc) + lane * 8];
    }
    const float maxn2 = __int_as_float(*maxbits);
    const float m_i   = sqrtf(norm2[(size_t)b * N_ + qrowc] * maxn2);
    float l_acc = 0.0f;
    f32x16 O0 = {0}, O1 = {0}, O2 = {0};

    // stage tile kt (Kh + V) into buffer nbuf (async DMA)
    auto stage = [&](int nbuf, int kt) {
        const u32 ktK = (u32)kt * 6144u;   // Kh: 6KB contiguous per tile
        const u32 ktV = (u32)kt * 64u;     // V: 32 tokens * 2B
#pragma unroll
        for (int j = 0; j < 4; j++) {
            int s = w + 4 * j;
            if (s >= 14) break;
            const char* sb = (s < 6) ? (const char*)fh + ktK
                                     : (const char*)vh + ktV;
            gload_lds16(sb + loff[j], (char*)&LDSU[nbuf][0] + dofs[j]);
        }
    };

    stage(0, kt0);
    __syncthreads();

    const int g16 = g * 16;
    int buf = 0;
    for (int kt = kt0; kt < kt1; kt++) {
        // (1) prefetch next tile into back buffer
        if (kt + 1 < kt1) stage(buf ^ 1, kt + 1);

        const char* Lb = (const char*)&LDSU[buf][0];

        // (2) Kl frags direct from global (coalesced, L1-hot) — issued
        //     before the MFMA chain so latency hides under Kh/QK work.
        short8 kl[6];
#pragma unroll
        for (int kc = 0; kc < 6; kc++)
            kl[kc] = *(const short8*)&fl[foff(kt, kc) + lane * 8];

        // (3) QK^T: Kh from LDS (sequential lane*16 — conflict-free)
        f32x16 S = {0};
        __builtin_amdgcn_s_setprio(1);
#pragma unroll
        for (int kc = 0; kc < 6; kc++) {
            short8 kh = *(const short8*)(Lb + kc * 1024 + lane * 16);
            S = __builtin_amdgcn_mfma_f32_32x32x16_bf16(kh, ql[kc], S, 0, 0, 0);
            S = __builtin_amdgcn_mfma_f32_32x32x16_bf16(kl[kc], qh[kc], S, 0, 0, 0);
            S = __builtin_amdgcn_mfma_f32_32x32x16_bf16(kh, qh[kc], S, 0, 0, 0);
        }
        __builtin_amdgcn_s_setprio(0);

        // (4) softmax numerators + bf16 pack
        float p[16];
#pragma unroll
        for (int r = 0; r < 16; r++) {
            p[r] = __expf(S[r] - m_i);
            l_acc += p[r];
        }
        u32 w8[8];
#pragma unroll
        for (int q = 0; q < 8; q++) w8[q] = packbf2(p[2 * q], p[2 * q + 1]);

        // (5) PV from V-LDS (80B rows: conflict-free)
        __builtin_amdgcn_s_setprio(1);
#pragma unroll
        for (int kc = 0; kc < 2; kc++) {
            const int qb = kc * 4;
            u32 a0 = w8[qb + 0], a1 = w8[qb + 1];
            u32 a2 = w8[qb + 2], a3 = w8[qb + 3];
            u32 s0 = __shfl_xor((int)a0, 32), s1 = __shfl_xor((int)a1, 32);
            u32 s2 = __shfl_xor((int)a2, 32), s3 = __shfl_xor((int)a3, 32);
            union { short8 v; u32 u[4]; } Bf;
            Bf.u[0] = g ? s2 : a0;
            Bf.u[1] = g ? s3 : a1;
            Bf.u[2] = g ? a2 : s0;
            Bf.u[3] = g ? a3 : s1;
            const int vo = K2_V_OFF + col * 80 + kc * 32 + g16;
            short8 v0 = *(const short8*)(Lb + vo);
            short8 v1 = *(const short8*)(Lb + vo + 2560);   // +32 ch
            short8 v2 = *(const short8*)(Lb + vo + 5120);   // +64 ch
            O0 = __builtin_amdgcn_mfma_f32_32x32x16_bf16(v0, Bf.v, O0, 0, 0, 0);
            O1 = __builtin_amdgcn_mfma_f32_32x32x16_bf16(v1, Bf.v, O1, 0, 0, 0);
            O2 = __builtin_amdgcn_mfma_f32_32x32x16_bf16(v2, Bf.v, O2, 0, 0, 0);
        }
        __builtin_amdgcn_s_setprio(0);

        __syncthreads();     // drains my DMAs + all waves' LDS reads done
        buf ^= 1;
    }

    if (qrow < N_) {
        float* ab = attT + (size_t)b * C_ * N_ + qrow;
#pragma unroll
        for (int r = 0; r < 16; r++) {
            int c = (r & 3) + 8 * (r >> 2) + 4 * g;
            atomicAdd(&ab[(size_t)(c)      * N_], O0[r]);
            atomicAdd(&ab[(size_t)(c + 32) * N_], O1[r]);
            atomicAdd(&ab[(size_t)(c + 64) * N_], O2[r]);
        }
        float l_tot = l_acc + __shfl_xor(l_acc, 32);
        if (g == 0) atomicAdd(&l_arr[(size_t)b * N_ + qrow], l_tot);
    }
}

// ---------------------------------------------------------------------------
// K3: MFMA 1x1 conv. R23: weight loads now from fragment-major wf arrays —
// single coalesced dwordx4 per frag (was 32-line gather x72 per wave).
// Geometry unchanged (784 blocks x 128 thr, verified R17).
__global__ __launch_bounds__(128, 3) void conv_mfma(const float* __restrict__ x,
                                                    const float* __restrict__ attT,
                                                    const float* __restrict__ l_arr,
                                                    const u16* __restrict__ wf_hi,
                                                    const u16* __restrict__ wf_lo,
                                                    const float* __restrict__ convb,
                                                    float* __restrict__ y) {
    __shared__ u16 ch[32 * CROW];
    __shared__ u16 cl[32 * CROW];
    __shared__ float invl[32];
    const int b   = blockIdx.x / (N_ / 32);
    const int n0  = (blockIdx.x % (N_ / 32)) * 32;
    const int tid = threadIdx.x;

    if (tid < 32) invl[tid] = 1.0f / l_arr[(size_t)b * N_ + n0 + tid];
    __syncthreads();

    const float* xb = x    + (size_t)b * C_ * N_ + n0;
    const float* ab = attT + (size_t)b * C_ * N_ + n0;
    for (int e = tid; e < 32 * C_; e += 128) {
        int c = e >> 5, t = e & 31;
        float xv = xb[(size_t)c * N_ + t];
        float au = ab[(size_t)c * N_ + t];
        float xj = fmaxf(xv - au * invl[t], 0.0f);
        u16 h1 = f2bf(xv);
        ch[t * CROW + c] = h1;
        cl[t * CROW + c] = f2bf(xv - bf2f(h1));
        u16 h2 = f2bf(xj);
        ch[t * CROW + C_ + c] = h2;
        cl[t * CROW + C_ + c] = f2bf(xj - bf2f(h2));
    }
    __syncthreads();

    const int lane = tid & 63;
    const int w    = tid >> 6;        // 0..1
    const int col  = lane & 31;       // token within tile
    const int g    = lane >> 5;
    const int m0   = w * 3;           // wave's 3 m-tiles (96 channels)

    f32x16 A[3] = {{0}, {0}, {0}};
#pragma unroll
    for (int ks = 0; ks < 12; ks++) {
        const int k0 = ks * 16;
        short8 bh = *(const short8*)&ch[col * CROW + k0 + g * 8];
        short8 bl = *(const short8*)&cl[col * CROW + k0 + g * 8];
#pragma unroll
        for (int mt = 0; mt < 3; mt++) {
            const size_t wo = (size_t)((m0 + mt) * 12 + ks) * 512 + lane * 8;
            short8 ah = *(const short8*)&wf_hi[wo];
            short8 al = *(const short8*)&wf_lo[wo];
            A[mt] = __builtin_amdgcn_mfma_f32_32x32x16_bf16(ah, bl, A[mt], 0, 0, 0);
            A[mt] = __builtin_amdgcn_mfma_f32_32x32x16_bf16(al, bh, A[mt], 0, 0, 0);
            A[mt] = __builtin_amdgcn_mfma_f32_32x32x16_bf16(ah, bh, A[mt], 0, 0, 0);
        }
    }

    float* yb = y + (size_t)b * COUT_ * N_ + n0 + col;
#pragma unroll
    for (int mt = 0; mt < 3; mt++)
#pragma unroll
        for (int r = 0; r < 16; r++) {
            int o = (m0 + mt) * 32 + (r & 3) + 8 * (r >> 2) + 4 * g;
            yb[(size_t)o * N_] = A[mt][r] + convb[o];
        }
}

// ---------------------------------------------------------------------------
// K4a: per-(b,channel) partial BN sums (distinct output lines, no contention)
__global__ __launch_bounds__(256) void bn_partial(const float* __restrict__ y,
                                                  float* __restrict__ pb) {
    const int o   = blockIdx.x;
    const int b   = blockIdx.y;
    const int tid = threadIdx.x;
    float s = 0.0f, q = 0.0f;
    const float4* p = (const float4*)(y + (size_t)(b * COUT_ + o) * N_);
    for (int i = tid; i < N_ / 4; i += 256) {
        float4 v = p[i];
        s += v.x + v.y + v.z + v.w;
        q += v.x * v.x + v.y * v.y + v.z * v.z + v.w * v.w;
    }
#pragma unroll
    for (int d = 1; d < 64; d <<= 1) {
        s += __shfl_xor(s, d);
        q += __shfl_xor(q, d);
    }
    __shared__ float wss[4], wqq[4];
    if ((tid & 63) == 0) { wss[tid >> 6] = s; wqq[tid >> 6] = q; }
    __syncthreads();
    if (tid == 0) {
        pb[b * COUT_ + o]                = wss[0] + wss[1] + wss[2] + wss[3];
        pb[B_ * COUT_ + b * COUT_ + o]   = wqq[0] + wqq[1] + wqq[2] + wqq[3];
    }
}

// K4b: reduce partials -> scale/shift
__global__ __launch_bounds__(192) void bn_finish(const float* __restrict__ pb,
                                                 const float* __restrict__ gamma,
                                                 const float* __restrict__ beta,
                                                 float* __restrict__ ss) {
    const int o = threadIdx.x;
    float s = 0.0f, q = 0.0f;
#pragma unroll
    for (int b = 0; b < B_; b++) {
        s += pb[b * COUT_ + o];
        q += pb[B_ * COUT_ + b * COUT_ + o];
    }
    const float invn = 1.0f / (float)NTOK_;
    float mean = s * invn;
    float var  = q * invn - mean * mean;
    float sc   = gamma[o] * rsqrtf(var + BN_EPS);
    ss[o]         = sc;
    ss[COUT_ + o] = beta[o] - mean * sc;
}

// K5: y -> BN affine -> exact GELU -> fp32 out
__global__ __launch_bounds__(256) void bn_gelu_out(const float* __restrict__ y,
                                                   const float* __restrict__ ss,
                                                   float* __restrict__ out) {
    const int total4 = (B_ * COUT_ * N_) / 4;
    int i = blockIdx.x * 256 + threadIdx.x;
    if (i >= total4) return;
    int base = i * 4;
    int o = (base / N_) % COUT_;
    float sc = ss[o], sh = ss[COUT_ + o];
    float4 v = *(const float4*)&y[base];
    float u0 = fmaf(v.x, sc, sh), u1 = fmaf(v.y, sc, sh);
    float u2 = fmaf(v.z, sc, sh), u3 = fmaf(v.w, sc, sh);
    const float k = 0.70710678118654752f;
    float4 g;
    g.x = 0.5f * u0 * (1.0f + erff(u0 * k));
    g.y = 0.5f * u1 * (1.0f + erff(u1 * k));
    g.z = 0.5f * u2 * (1.0f + erff(u2 * k));
    g.w = 0.5f * u3 * (1.0f + erff(u3 * k));
    *(float4*)&out[base] = g;
}

// ---------------------------------------------------------------------------
extern "C" void kernel_launch(void* const* d_in, const int* in_sizes, int n_in,
                              void* d_out, int out_size, void* d_ws, size_t ws_size,
                              hipStream_t stream) {
    const float* x     = (const float*)d_in[0];
    const float* w     = (const float*)d_in[1];
    const float* cb    = (const float*)d_in[2];
    const float* gamma = (const float*)d_in[3];
    const float* beta  = (const float*)d_in[4];

    u16* xf_hi = (u16*)d_ws;                         // BNC bf16 (fragment-major)
    u16* xf_lo = xf_hi + (size_t)BNC;                // BNC
    u16* xc_hi = xf_lo + (size_t)BNC;                // BNC (channel-major, V)
    float* attT  = (float*)(xc_hi + (size_t)BNC);    // BNC fp32
    u16* wf_hi = (u16*)(attT + (size_t)BNC);         // 192*192 bf16 (fragment-major)
    u16* wf_lo = wf_hi + COUT_ * 2 * C_;             // 192*192 bf16
    float* y     = (float*)(wf_lo + COUT_ * 2 * C_); // B*COUT*N fp32
    float* ss    = y + (size_t)B_ * COUT_ * N_;      // 2*COUT
    float* l_arr = ss + 2 * COUT_;                   // NTOK
    float* norm2 = l_arr + NTOK_;                    // NTOK
    int*   maxb  = (int*)(norm2 + NTOK_);            // 1
    float* pb    = attT;                             // 2*B*COUT partials (attT dead after conv)

    hipMemsetAsync(l_arr, 0, NTOK_ * sizeof(float), stream);
    hipMemsetAsync(norm2, 0, NTOK_ * sizeof(float), stream);
    hipMemsetAsync(maxb, 0, sizeof(int), stream);
    hipMemsetAsync(attT, 0, (size_t)BNC * sizeof(float), stream);

    transpose_split<<<dim3(N_ / 32, C_ / 32, B_), 256, 0, stream>>>(x, xf_hi, xf_lo, xc_hi, norm2);
    cast_w<<<dim3((COUT_ * 2 * C_ + 255) / 256), 256, 0, stream>>>(w, wf_hi, wf_lo);
    norm_max<<<dim3(25), 256, 0, stream>>>(norm2, maxb);
    flash_attn_mfma32<<<dim3((N_ + 127) / 128, B_, NSPLIT), 256, 0, stream>>>(
        xf_hi, xf_lo, xc_hi, norm2, maxb, attT, l_arr);
    conv_mfma<<<dim3(B_ * (N_ / 32)), 128, 0, stream>>>(x, attT, l_arr, wf_hi, wf_lo, cb, y);
    bn_partial<<<dim3(COUT_, B_), 256, 0, stream>>>(y, pb);
    bn_finish<<<dim3(1), 192, 0, stream>>>(pb, gamma, beta, ss);
    bn_gelu_out<<<dim3((B_ * COUT_ * N_ / 4 + 255) / 256), 256, 0, stream>>>(y, ss, (float*)d_out);
}